// Round 11
// baseline (366.155 us; speedup 1.0000x reference)
//
#include <hip/hip_runtime.h>
#include <hip/hip_bf16.h>

// ---------------------------------------------------------------------------
// MessagePassing (e3nn scalar conv, 2 layers) on MI355X. Inputs f32, out f32.
// Round 22 (base r21, 362.9us): disentangle r21's confounded pair.
//  * KEEP: k_perm fused into k_edge_w layer 0 (k_perm launch deleted - the
//    win component).
//  * REVERT: k_edge_w block 128->256 (4 waves, SCR[4][8704], grid 3125).
//    r21's 128-thread blocks cost +28MB WRITE_SIZE on BOTH layers (ef
//    scatter-write L2 write-combining worsened; 87.5->106us per dispatch).
//    256-block form is triple-verified at ~87.5us / 87.7MB writes.
//  * everything else identical to r21.
// ---------------------------------------------------------------------------

namespace {
constexpr int NN = 50000;
constexpr int NE = 800000;
constexpr int SCAN_BLOCKS = 196;     // ceil(50000/256)

// ws layout (float indices) - ORIGINAL, verified footprint
constexpr long OFF_NF   = 0;         // f32 [1,600,000] inter-layer nf
constexpr long OFF_W0P  = 1600000;   // ushort[4096]
constexpr long OFF_W2P  = 1602048;   // ushort[16384]
constexpr long OFF_WNP  = 1610240;   // ushort[57344] node-GEMM B-frags
constexpr long OFF_OFF  = 1638912;   // int [50001]
constexpr long OFF_CUR  = 1688913;   // int [50000]
constexpr long OFF_PERM = 1738913;   // int [800000]
constexpr long OFF_BSUM = 2538913;   // int [256] block sums
constexpr long OFF_EF   = 2539172;   // ushort [25,600,000] (16-B aligned)
}

typedef __attribute__((ext_vector_type(8))) short short8;
typedef __attribute__((ext_vector_type(4))) float f32x4;
typedef __attribute__((ext_vector_type(2))) float f32x2;
typedef f32x2 __attribute__((may_alias)) f32x2a;
typedef unsigned int   __attribute__((may_alias)) u32a;
typedef unsigned short __attribute__((may_alias)) u16a;
typedef float          __attribute__((may_alias)) f32a;

__device__ __forceinline__ float us2f(unsigned int u) {
    unsigned int x = u << 16; float f;
    __builtin_memcpy(&f, &x, sizeof(f));
    return f;
}
__device__ __forceinline__ unsigned short f2us(float f) {
    __hip_bfloat16 h = __float2bfloat16(f);
    unsigned short s;
    __builtin_memcpy(&s, &h, sizeof(s));
    return s;
}
__device__ __forceinline__ f32x2 mk2(float a, float b) {
    f32x2 r; r[0] = a; r[1] = b; return r;
}
__device__ __forceinline__ f32x2 pkfma(f32x2 a, f32x2 b, f32x2 c) {
#if __has_builtin(__builtin_elementwise_fma)
    return __builtin_elementwise_fma(a, b, c);
#else
    f32x2 r; r[0] = fmaf(a[0], b[0], c[0]); r[1] = fmaf(a[1], b[1], c[1]);
    return r;
#endif
}

// ------------- hist + all weight packing ------------------------------------
__global__ __launch_bounds__(256) void k_hist(
        const int* __restrict__ dst, int* __restrict__ cnt,
        const float* __restrict__ f0, const float* __restrict__ f1,
        const float* __restrict__ l1w, const float* __restrict__ scw,
        const float* __restrict__ l2w, const float* __restrict__ aw,
        unsigned short* __restrict__ w0p, unsigned short* __restrict__ w2p,
        unsigned short* __restrict__ wnp) {
    int i = blockIdx.x * 256 + threadIdx.x;
    if (i < NE) atomicAdd(&cnt[dst[i]], 1);
    if (i < 4096) {                     // w0p [l][nt4][lane][i8], 0.25 folded
        int l = i >> 11, r = i & 2047;
        int nt = r >> 9, lane = (r >> 3) & 63, ii = r & 7;
        int k = (lane >> 4) * 8 + ii;
        int j = nt * 16 + (lane & 15);
        float v = (k < 16) ? 0.25f * f0[l * 1024 + k * 64 + j] : 0.f;
        w0p[i] = f2us(v);
    }
    if (i < 16384) {                    // w2p [l][kt*2+nt][lane][i8]
        int l = i >> 13, r = i & 8191;
        int g = r >> 9;
        int kt = g >> 1, nt = g & 1;
        int lane = (r >> 3) & 63, ii = r & 7;
        int K = kt * 32 + (lane >> 4) * 8 + ii;
        int j = K >> 2, v = K & 3;
        int u = nt * 16 + (lane & 15);
        w2p[i] = f2us(f1[l * 8192 + j * 128 + u * 4 + v]);
    }
    if (i < 57344) {                    // wnp [l][tile7][kt8][lane][i8]
        int l = i / 28672, r = i % 28672;
        int tile = r >> 12;
        int r2 = r & 4095;
        int kt = r2 >> 9, lane = (r2 >> 3) & 63, ii = r2 & 7;
        int k = kt * 32 + (lane >> 4) * 8 + ii;   // K = u*8+v
        int u = k >> 3, v = k & 7;
        int col = lane & 15;
        int uvb = l * 8192 + (u * 8 + v) * 32;
        float val;
        if (tile < 2)      val = l1w[uvb + tile * 16 + col];
        else if (tile < 4) val = scw[uvb + (tile - 2) * 16 + col];
        else if (tile < 6) val = l2w[uvb + (tile - 4) * 16 + col];
        else               val = (col == 0) ? aw[l * 256 + u * 8 + v] : 0.f;
        wnp[i] = f2us(val);
    }
}

// ------------------------- 3-phase parallel scan ----------------------------
__global__ __launch_bounds__(256) void k_scan1(const int* __restrict__ cnt,
                                               int* __restrict__ bsum) {
    __shared__ int s[256];
    int t = threadIdx.x;
    int i = blockIdx.x * 256 + t;
    s[t] = (i < NN) ? cnt[i] : 0;
    __syncthreads();
    for (int d = 128; d > 0; d >>= 1) {
        if (t < d) s[t] += s[t + d];
        __syncthreads();
    }
    if (t == 0) bsum[blockIdx.x] = s[0];
}

__global__ __launch_bounds__(256) void k_scan2(int* __restrict__ bsum) {
    __shared__ int s[256];
    int t = threadIdx.x;
    int v = (t < SCAN_BLOCKS) ? bsum[t] : 0;
    s[t] = v; __syncthreads();
    for (int d = 1; d < 256; d <<= 1) {
        int x = (t >= d) ? s[t - d] : 0;
        __syncthreads();
        s[t] += x;
        __syncthreads();
    }
    if (t < SCAN_BLOCKS) bsum[t] = s[t] - v;   // exclusive
}

__global__ __launch_bounds__(256) void k_scan3(
        const int* __restrict__ cnt, const int* __restrict__ bsum,
        int* __restrict__ off, int* __restrict__ cur) {
    __shared__ int s[256];
    int t = threadIdx.x;
    int i = blockIdx.x * 256 + t;
    int v = (i < NN) ? cnt[i] : 0;
    s[t] = v; __syncthreads();
    for (int d = 1; d < 256; d <<= 1) {
        int x = (t >= d) ? s[t - d] : 0;
        __syncthreads();
        s[t] += x;
        __syncthreads();
    }
    int excl = s[t] - v + bsum[blockIdx.x];
    if (i < NN) { off[i] = excl; cur[i] = excl; }
    if (i == NN - 1) off[NN] = excl + v;       // == NE
}

// ---- wave-local staging: wave w stages node rows w*16 .. w*16+15 -----------
__device__ __forceinline__ void stage_xy_wl(const float* __restrict__ nf,
                                            const float* __restrict__ nattr,
                                            long n0, int w, int lane,
                                            f32a* Xs, f32a* Ys) {
    {
        int row = w * 16 + (lane >> 2), u = (lane & 3) * 8;
        long e = (n0 + row) * 32 + u;
        f32a* d = &Xs[row * 33 + u];
        if (e + 8 <= (long)NN * 32) {
            const float4* p = (const float4*)(nf + e);
            float4 q0 = p[0], q1 = p[1];
            d[0]=q0.x; d[1]=q0.y; d[2]=q0.z; d[3]=q0.w;
            d[4]=q1.x; d[5]=q1.y; d[6]=q1.z; d[7]=q1.w;
        } else {
#pragma unroll
            for (int i = 0; i < 8; i++)
                d[i] = (e + i < (long)NN * 32) ? nf[e + i] : 0.f;
        }
    }
    if (lane < 32) {
        int row = w * 16 + (lane >> 1), v = (lane & 1) * 4;
        long e = (n0 + row) * 8 + v;
        f32a* d = &Ys[row * 9 + v];
        if (e + 4 <= (long)NN * 8) {
            float4 q = *(const float4*)(nattr + e);
            d[0]=q.x; d[1]=q.y; d[2]=q.z; d[3]=q.w;
        } else {
#pragma unroll
            for (int i = 0; i < 4; i++)
                d[i] = (e + i < (long)NN * 8) ? nattr[e + i] : 0.f;
        }
    }
}

// ------------- node pre (MFMA): xl = lin1(nf, nattr), layer 0 only ----------
__global__ __launch_bounds__(256) void k_npre_m(
        const float* __restrict__ nf, const float* __restrict__ nattr,
        const unsigned short* __restrict__ wnp_l, float* __restrict__ xl) {
    __shared__ f32a Xs[64 * 33];
    __shared__ f32a Ys[64 * 9];
    const int t = threadIdx.x;
    const int lane = t & 63, w = t >> 6;
    const long n0 = (long)blockIdx.x * 64;
    stage_xy_wl(nf, nattr, n0, w, lane, Xs, Ys);
    __builtin_amdgcn_wave_barrier();   // wave-local LDS; DS pipe in-order

    const int l15 = lane & 15, quad = lane >> 4;
    const int nb = w * 16;
    float y[8], xk[8];
#pragma unroll
    for (int v = 0; v < 8; v++) y[v] = Ys[(nb + l15) * 9 + v];
#pragma unroll
    for (int kt = 0; kt < 8; kt++) xk[kt] = Xs[(nb + l15) * 33 + kt * 4 + quad];

    f32x4 a0, a1;
    a0[0]=0.f;a0[1]=0.f;a0[2]=0.f;a0[3]=0.f;
    a1[0]=0.f;a1[1]=0.f;a1[2]=0.f;a1[3]=0.f;
#pragma unroll
    for (int kt = 0; kt < 8; kt++) {
        float xv = xk[kt];
        short8 a;
#pragma unroll
        for (int i = 0; i < 8; i++) a[i] = (short)f2us(xv * y[i]);
        const short8 b0 = *(const short8*)(wnp_l + ((0 * 8 + kt) * 512) + lane * 8);
        const short8 b1 = *(const short8*)(wnp_l + ((1 * 8 + kt) * 512) + lane * 8);
        a0 = __builtin_amdgcn_mfma_f32_16x16x32_bf16(a, b0, a0, 0, 0, 0);
        a1 = __builtin_amdgcn_mfma_f32_16x16x32_bf16(a, b1, a1, 0, 0, 0);
    }
#pragma unroll
    for (int r = 0; r < 4; r++) {
        long n = n0 + nb + quad * 4 + r;
        if (n < NN) {
            xl[n * 32 + l15]      = a0[r] * 0.0625f;
            xl[n * 32 + 16 + l15] = a1[r] * 0.0625f;
        }
    }
}

// ------------- per-wave edge kernel (r22: 4-wave blocks + fused perm) -------
__global__ __launch_bounds__(256) void k_edge_w(
        const float* __restrict__ esc, const int* __restrict__ srcp,
        const int* __restrict__ edst, int* __restrict__ cur,
        int* __restrict__ perm, int do_perm,
        const float* __restrict__ ea_in,
        float* __restrict__ ea_out, const float* __restrict__ xl,
        const unsigned short* __restrict__ w0p,
        const unsigned short* __restrict__ w2p,
        const float* __restrict__ sew, unsigned short* __restrict__ ef_bf) {
    __shared__ __align__(16) unsigned char SCR[4][8704];

    const int t = threadIdx.x;
    const int w = t >> 6, lane = t & 63;
    const int l15 = lane & 15, quad = lane >> 4;
    const long e0 = ((long)blockIdx.x * 4 + w) * 64;
    u16a* Hs = (u16a*)SCR[w];
    f32a* Ts = (f32a*)SCR[w];

    // ---- entry: scalars + ea rows; layer 0 computes perm itself ------------
    const long ge = e0 + lane;
    const int src = srcp[ge];
    int pm;
    if (do_perm) {                       // wave-uniform branch
        pm = atomicAdd(&cur[edst[ge]], 1);   // result unused until epilogue
        perm[ge] = pm;                       // saved for layer 1
    } else {
        pm = perm[ge];
    }
    const float4 ea3 = ((const float4*)ea_in)[ge];
    float4 eaq[4];
#pragma unroll
    for (int mt = 0; mt < 4; mt++)
        eaq[mt] = ((const float4*)ea_in)[e0 + mt * 16 + l15];

    // ---- phase 1: H = sin(esc @ w0) -> Hs (bf16) ---------------------------
    short8 bw0[4];
#pragma unroll
    for (int nt = 0; nt < 4; nt++)
        bw0[nt] = *(const short8*)(w0p + (nt * 64 + lane) * 8);
#pragma unroll
    for (int mt = 0; mt < 4; mt++) {
        int row = mt * 16 + l15;
        short8 a;
#pragma unroll
        for (int i = 0; i < 8; i++) a[i] = 0;
        if (quad < 2) {
            const float4* ep = (const float4*)(esc + (e0 + row) * 16 + quad * 8);
            float4 p0 = ep[0], p1 = ep[1];
            a[0]=(short)f2us(p0.x); a[1]=(short)f2us(p0.y);
            a[2]=(short)f2us(p0.z); a[3]=(short)f2us(p0.w);
            a[4]=(short)f2us(p1.x); a[5]=(short)f2us(p1.y);
            a[6]=(short)f2us(p1.z); a[7]=(short)f2us(p1.w);
        }
#pragma unroll
        for (int nt = 0; nt < 4; nt++) {
            f32x4 c; c[0]=0.f; c[1]=0.f; c[2]=0.f; c[3]=0.f;
            c = __builtin_amdgcn_mfma_f32_16x16x32_bf16(a, bw0[nt], c, 0, 0, 0);
#pragma unroll
            for (int r = 0; r < 4; r++) {
                int edge = mt * 16 + quad * 4 + r;
                int j = nt * 16 + l15;
                Hs[edge * 68 + j] = f2us(__sinf(c[r]));
            }
        }
    }
    // per-wave LDS only: compiler fence (0 instrs); DS pipe is in-order.
    __builtin_amdgcn_wave_barrier();

    // ---- issue xl gather now; lands under phase-2 MFMA ---------------------
    const float4* xp = (const float4*)(xl + (long)src * 32);
    float4 xq[8];
#pragma unroll
    for (int g = 0; g < 8; g++) xq[g] = xp[g];

    // ---- phase 2: T = (H (x) ea) @ w2, kt-outer so B-frags load once -------
    f32x4 acc[4][2];
#pragma unroll
    for (int mt = 0; mt < 4; mt++)
#pragma unroll
        for (int nt = 0; nt < 2; nt++) {
            acc[mt][nt][0]=0.f; acc[mt][nt][1]=0.f;
            acc[mt][nt][2]=0.f; acc[mt][nt][3]=0.f;
        }
#pragma unroll
    for (int kt = 0; kt < 8; kt++) {
        const short8 b0 = *(const short8*)(w2p + ((kt*2+0)*64 + lane) * 8);
        const short8 b1 = *(const short8*)(w2p + ((kt*2+1)*64 + lane) * 8);
#pragma unroll
        for (int mt = 0; mt < 4; mt++) {
            int row = mt * 16 + l15;
            unsigned int hp = *(const u32a*)(Hs + row * 68 + kt * 8 + quad * 2);
            float H0 = us2f(hp & 0xFFFFu), H1 = us2f(hp >> 16);
            float4 eav = eaq[mt];
            short8 a;
            a[0]=(short)f2us(H0*eav.x); a[1]=(short)f2us(H0*eav.y);
            a[2]=(short)f2us(H0*eav.z); a[3]=(short)f2us(H0*eav.w);
            a[4]=(short)f2us(H1*eav.x); a[5]=(short)f2us(H1*eav.y);
            a[6]=(short)f2us(H1*eav.z); a[7]=(short)f2us(H1*eav.w);
            acc[mt][0] = __builtin_amdgcn_mfma_f32_16x16x32_bf16(a, b0, acc[mt][0], 0, 0, 0);
            acc[mt][1] = __builtin_amdgcn_mfma_f32_16x16x32_bf16(a, b1, acc[mt][1], 0, 0, 0);
        }
    }
    __builtin_amdgcn_wave_barrier();

    // ---- phase 3: transpose T via LDS (0.5 of ef folded into scale) --------
#pragma unroll
    for (int mt = 0; mt < 4; mt++)
#pragma unroll
        for (int nt = 0; nt < 2; nt++)
#pragma unroll
            for (int r = 0; r < 4; r++)
                Ts[(mt*16 + quad*4 + r) * 34 + nt*16 + l15] = acc[mt][nt][r] * 0.0625f;
    __builtin_amdgcn_wave_barrier();

    // ---- epilogue: tvp/efp pairs + k-pair pk eo (r19 verified) -------------
    {
        f32x2 tvp[16];
#pragma unroll
        for (int i = 0; i < 16; i++)
            tvp[i] = *(const f32x2a*)(Ts + lane * 34 + i * 2);   // ds_read_b64
        f32x2 efp[16];
#pragma unroll
        for (int g = 0; g < 8; g++) {
            float4 xv = xq[g];
            efp[2*g]   = mk2(xv.x, xv.y) * tvp[2*g];
            efp[2*g+1] = mk2(xv.z, xv.w) * tvp[2*g+1];
        }
        uint4* efo = (uint4*)(ef_bf + (long)pm * 32);
#pragma unroll
        for (int g = 0; g < 4; g++) {
            uint4 wv;
            wv.x = (unsigned)f2us(efp[4*g+0][0]) | ((unsigned)f2us(efp[4*g+0][1]) << 16);
            wv.y = (unsigned)f2us(efp[4*g+1][0]) | ((unsigned)f2us(efp[4*g+1][1]) << 16);
            wv.z = (unsigned)f2us(efp[4*g+2][0]) | ((unsigned)f2us(efp[4*g+2][1]) << 16);
            wv.w = (unsigned)f2us(efp[4*g+3][0]) | ((unsigned)f2us(efp[4*g+3][1]) << 16);
            efo[g] = wv;
        }
        float ea[4] = {ea3.x, ea3.y, ea3.z, ea3.w};
        f32x2 eo01 = {0.f, 0.f}, eo23 = {0.f, 0.f};
#pragma unroll
        for (int u = 0; u < 32; u++) {
            float efu = efp[u >> 1][u & 1];
#pragma unroll
            for (int v = 0; v < 4; v++) {
                float p = efu * ea[v];
                f32x2 pp = mk2(p, p);
                const f32x2 s01 = *(const f32x2a*)(sew + (u * 4 + v) * 4);
                const f32x2 s23 = *(const f32x2a*)(sew + (u * 4 + v) * 4 + 2);
                eo01 = pkfma(pp, s01, eo01);
                eo23 = pkfma(pp, s23, eo23);
            }
        }
        constexpr float SCE_SCALE = 0.02209708691f;
        float4 o;
        o.x = ea3.x + eo01[0] * SCE_SCALE;
        o.y = ea3.y + eo01[1] * SCE_SCALE;
        o.z = ea3.z + eo23[0] * SCE_SCALE;
        o.w = ea3.w + eo23[1] * SCE_SCALE;
        ((float4*)ea_out)[ge] = o;
    }
}

// --------- gather (16 lanes/node) + node post + fused next-layer npre -------
__global__ __launch_bounds__(256) void k_gpost_m(
        const int* __restrict__ off, const unsigned short* __restrict__ ef,
        const float* __restrict__ nf_cur, const float* __restrict__ nattr,
        const unsigned short* __restrict__ wnp_l,
        float* __restrict__ nf_next, float* __restrict__ out_nf, int last,
        const unsigned short* __restrict__ wnp_next,
        float* __restrict__ xl_out) {
    __shared__ f32a Xs[64 * 33];
    __shared__ f32a As[64 * 33];
    __shared__ f32a Ys[64 * 9];
    const int t = threadIdx.x;
    const int lane = t & 63, w = t >> 6;
    const long n0 = (long)blockIdx.x * 64;
    stage_xy_wl(nf_cur, nattr, n0, w, lane, Xs, Ys);

    {   // gather: 16 lanes/node, 4 r-interleaved streams (serial chain ~4)
        int g = (lane >> 2) & 3, l4 = lane & 3;
#pragma unroll
        for (int batch = 0; batch < 4; batch++) {
            int nl = w * 16 + batch * 4 + (lane >> 4);
            long n = n0 + nl;
            float v[8] = {0.f,0.f,0.f,0.f,0.f,0.f,0.f,0.f};
            if (n < NN) {
                int b = off[n] + g, en = off[n + 1];
                for (int r = b; r < en; r += 4) {
                    uint4 q = *(const uint4*)(ef + (long)r * 32 + l4 * 8);
                    v[0] += us2f(q.x & 0xFFFFu); v[1] += us2f(q.x >> 16);
                    v[2] += us2f(q.y & 0xFFFFu); v[3] += us2f(q.y >> 16);
                    v[4] += us2f(q.z & 0xFFFFu); v[5] += us2f(q.z >> 16);
                    v[6] += us2f(q.w & 0xFFFFu); v[7] += us2f(q.w >> 16);
                }
            }
#pragma unroll
            for (int i = 0; i < 8; i++) {
                v[i] += __shfl_xor(v[i], 4);
                v[i] += __shfl_xor(v[i], 8);
            }
            if (g == 0) {
#pragma unroll
                for (int i = 0; i < 8; i++)
                    As[nl * 33 + l4 * 8 + i] = v[i] * 0.25f;
            }
        }
    }
    __builtin_amdgcn_wave_barrier();   // all LDS wave-local

    const int l15 = lane & 15, quad = lane >> 4;
    const int nb = w * 16;
    float y[8], xk[8], ak[8];
#pragma unroll
    for (int v = 0; v < 8; v++) y[v] = Ys[(nb + l15) * 9 + v];
#pragma unroll
    for (int kt = 0; kt < 8; kt++) {
        xk[kt] = Xs[(nb + l15) * 33 + kt * 4 + quad];
        ak[kt] = As[(nb + l15) * 33 + kt * 4 + quad];
    }
    f32x4 sc0, sc1, l20, l21, al;
    sc0[0]=0.f;sc0[1]=0.f;sc0[2]=0.f;sc0[3]=0.f;
    sc1 = sc0; l20 = sc0; l21 = sc0; al = sc0;
#pragma unroll
    for (int kt = 0; kt < 8; kt++) {
        float xv = xk[kt], av = ak[kt];
        short8 ax, ag;
#pragma unroll
        for (int i = 0; i < 8; i++) {
            ax[i] = (short)f2us(xv * y[i]);
            ag[i] = (short)f2us(av * y[i]);
        }
        const short8 b2 = *(const short8*)(wnp_l + ((2 * 8 + kt) * 512) + lane * 8);
        const short8 b3 = *(const short8*)(wnp_l + ((3 * 8 + kt) * 512) + lane * 8);
        const short8 b4 = *(const short8*)(wnp_l + ((4 * 8 + kt) * 512) + lane * 8);
        const short8 b5 = *(const short8*)(wnp_l + ((5 * 8 + kt) * 512) + lane * 8);
        const short8 b6 = *(const short8*)(wnp_l + ((6 * 8 + kt) * 512) + lane * 8);
        sc0 = __builtin_amdgcn_mfma_f32_16x16x32_bf16(ax, b2, sc0, 0, 0, 0);
        sc1 = __builtin_amdgcn_mfma_f32_16x16x32_bf16(ax, b3, sc1, 0, 0, 0);
        l20 = __builtin_amdgcn_mfma_f32_16x16x32_bf16(ag, b4, l20, 0, 0, 0);
        l21 = __builtin_amdgcn_mfma_f32_16x16x32_bf16(ag, b5, l21, 0, 0, 0);
        al  = __builtin_amdgcn_mfma_f32_16x16x32_bf16(ag, b6, al,  0, 0, 0);
    }
#pragma unroll
    for (int r = 0; r < 4; r++) {
        float alpha = __shfl(al[r], quad * 16) * 0.0625f;  // col 0 of alpha tile
        long n = n0 + nb + quad * 4 + r;
        float o0 = sc0[r] * 0.0625f + alpha * (l20[r] * 0.0625f);
        float o1 = sc1[r] * 0.0625f + alpha * (l21[r] * 0.0625f);
        if (last) {
            if (n < NN) {
                out_nf[n * 32 + l15]      = o0;
                out_nf[n * 32 + 16 + l15] = o1;
            }
        } else {
            float t0 = __sinf(o0), t1 = __sinf(o1);
            if (n < NN) {
                nf_next[n * 32 + l15]      = t0;
                nf_next[n * 32 + 16 + l15] = t1;
            }
            // stage next-layer X into wave-local Xs (xk already consumed)
            Xs[(nb + quad * 4 + r) * 33 + l15]      = t0;
            Xs[(nb + quad * 4 + r) * 33 + 16 + l15] = t1;
        }
    }
    if (!last) {   // fused next-layer npre: xl_out = lin1_{l+1}(sin(o), nattr)
        __builtin_amdgcn_wave_barrier();
        float xk2[8];
#pragma unroll
        for (int kt = 0; kt < 8; kt++)
            xk2[kt] = Xs[(nb + l15) * 33 + kt * 4 + quad];
        f32x4 a0, a1;
        a0[0]=0.f;a0[1]=0.f;a0[2]=0.f;a0[3]=0.f;
        a1 = a0;
#pragma unroll
        for (int kt = 0; kt < 8; kt++) {
            float xv = xk2[kt];
            short8 a;
#pragma unroll
            for (int i = 0; i < 8; i++) a[i] = (short)f2us(xv * y[i]);
            const short8 b0 = *(const short8*)(wnp_next + ((0 * 8 + kt) * 512) + lane * 8);
            const short8 b1 = *(const short8*)(wnp_next + ((1 * 8 + kt) * 512) + lane * 8);
            a0 = __builtin_amdgcn_mfma_f32_16x16x32_bf16(a, b0, a0, 0, 0, 0);
            a1 = __builtin_amdgcn_mfma_f32_16x16x32_bf16(a, b1, a1, 0, 0, 0);
        }
#pragma unroll
        for (int r = 0; r < 4; r++) {
            long n = n0 + nb + quad * 4 + r;
            if (n < NN) {
                xl_out[n * 32 + l15]      = a0[r] * 0.0625f;
                xl_out[n * 32 + 16 + l15] = a1[r] * 0.0625f;
            }
        }
    }
}

// ---------------------------------------------------------------------------
extern "C" void kernel_launch(void* const* d_in, const int* in_sizes, int n_in,
                              void* d_out, int out_size, void* d_ws, size_t ws_size,
                              hipStream_t stream) {
    int I_nf, I_na, I_esrc, I_edst, I_ea, I_esc, I_sc, I_l1, I_l2, I_al, I_se, I_f0, I_f1;
    if (in_sizes[0] == 1600000) {            // dict order
        I_nf=0; I_na=1; I_esrc=2; I_edst=3; I_ea=4; I_esc=5;
        I_sc=6; I_l1=7; I_l2=8; I_al=9; I_se=10; I_f0=11; I_f1=12;
    } else {                                  // sorted keys
        I_al=0; I_ea=1; I_edst=2; I_esc=3; I_esrc=4; I_f0=5; I_f1=6;
        I_l1=7; I_l2=8; I_na=9; I_nf=10; I_sc=11; I_se=12;
    }
    const float* nf_in = (const float*)d_in[I_nf];
    const float* na    = (const float*)d_in[I_na];
    const int*   esrc  = (const int*)d_in[I_esrc];
    const int*   edst  = (const int*)d_in[I_edst];
    const float* ea_in = (const float*)d_in[I_ea];
    const float* escl  = (const float*)d_in[I_esc];
    const float* w_sc  = (const float*)d_in[I_sc];
    const float* w_l1  = (const float*)d_in[I_l1];
    const float* w_l2  = (const float*)d_in[I_l2];
    const float* w_al  = (const float*)d_in[I_al];
    const float* w_se  = (const float*)d_in[I_se];
    const float* w_f0  = (const float*)d_in[I_f0];
    const float* w_f1  = (const float*)d_in[I_f1];

    float* ws = (float*)d_ws;
    float* out_nf = (float*)d_out;              // f32 [50000*32]
    float* out_ea = out_nf + (long)NN * 32;     // f32 [800000*4]

    unsigned short* w0p     = (unsigned short*)(ws + OFF_W0P);
    unsigned short* w2p     = (unsigned short*)(ws + OFF_W2P);
    unsigned short* wnp     = (unsigned short*)(ws + OFF_WNP);
    int*            csr_off = (int*)(ws + OFF_OFF);
    int*            csr_cur = (int*)(ws + OFF_CUR);
    int*            perm    = (int*)(ws + OFF_PERM);
    int*            bsum    = (int*)(ws + OFF_BSUM);
    unsigned short* ef_bf   = (unsigned short*)(ws + OFF_EF);

    hipMemsetAsync(csr_cur, 0, NN * sizeof(int), stream);
    k_hist<<<3125, 256, 0, stream>>>(edst, csr_cur, w_f0, w_f1,
                                     w_l1, w_sc, w_l2, w_al, w0p, w2p, wnp);
    k_scan1<<<SCAN_BLOCKS, 256, 0, stream>>>(csr_cur, bsum);
    k_scan2<<<1, 256, 0, stream>>>(bsum);
    k_scan3<<<SCAN_BLOCKS, 256, 0, stream>>>(csr_cur, bsum, csr_off, csr_cur);
    // k_perm fused into k_edge_w layer 0

    for (int l = 0; l < 2; l++) {
        int last = (l == 1);
        const float* nf_cur = (l == 0) ? nf_in : (ws + OFF_NF);
        const float* ea_cur = (l == 0) ? ea_in : out_ea;

        if (l == 0)
            k_npre_m<<<782, 256, 0, stream>>>(nf_cur, na, wnp,
                                              out_nf /*xl scratch*/);
        k_edge_w<<<3125, 256, 0, stream>>>(escl, esrc, edst, csr_cur,
                                           perm, (l == 0) ? 1 : 0,
                                           ea_cur, out_ea,
                                           out_nf /*xl*/, w0p + l * 2048,
                                           w2p + l * 8192, w_se + l * 512,
                                           ef_bf);
        k_gpost_m<<<782, 256, 0, stream>>>(csr_off, ef_bf,
                                           nf_cur, na, wnp + l * 28672,
                                           ws + OFF_NF, out_nf, last,
                                           wnp + 28672 /*next layer*/,
                                           out_nf /*xl for next layer*/);
    }
}

// Round 12
// 354.473 us; speedup vs baseline: 1.0330x; 1.0330x over previous
//
#include <hip/hip_runtime.h>
#include <hip/hip_bf16.h>

// ---------------------------------------------------------------------------
// MessagePassing (e3nn scalar conv, 2 layers) on MI355X. Inputs f32, out f32.
// Round 23 (base r22, 366.2us): fix the perm-fusion write amplification.
// r22's entry atomicAdd in k_edge_w scrambled ef scatter-slot order ->
// paired 128B-line slots written ~6us apart -> L2 write-combining broke
// (+28MB WRITE_SIZE, 87.5->105us). Fix: slot RANK assigned in k_hist
// (its atomicAdd return value, issued in the same tight-burst near-edge-
// order as the old standalone k_perm) and stored; k_edge_w computes
// pm = off[edst[e]] + rank[e] with plain loads (off is L2-resident 200KB).
// No atomic in the hot kernel, no k_perm launch, no ws change (rank
// reuses the perm slot). Both layers identical.
// ---------------------------------------------------------------------------

namespace {
constexpr int NN = 50000;
constexpr int NE = 800000;
constexpr int SCAN_BLOCKS = 196;     // ceil(50000/256)

// ws layout (float indices) - ORIGINAL, verified footprint
constexpr long OFF_NF   = 0;         // f32 [1,600,000] inter-layer nf
constexpr long OFF_W0P  = 1600000;   // ushort[4096]
constexpr long OFF_W2P  = 1602048;   // ushort[16384]
constexpr long OFF_WNP  = 1610240;   // ushort[57344] node-GEMM B-frags
constexpr long OFF_OFF  = 1638912;   // int [50001]
constexpr long OFF_CUR  = 1688913;   // int [50000]
constexpr long OFF_PERM = 1738913;   // int [800000]  (now: rank[e])
constexpr long OFF_BSUM = 2538913;   // int [256] block sums
constexpr long OFF_EF   = 2539172;   // ushort [25,600,000] (16-B aligned)
}

typedef __attribute__((ext_vector_type(8))) short short8;
typedef __attribute__((ext_vector_type(4))) float f32x4;
typedef __attribute__((ext_vector_type(2))) float f32x2;
typedef f32x2 __attribute__((may_alias)) f32x2a;
typedef unsigned int   __attribute__((may_alias)) u32a;
typedef unsigned short __attribute__((may_alias)) u16a;
typedef float          __attribute__((may_alias)) f32a;

__device__ __forceinline__ float us2f(unsigned int u) {
    unsigned int x = u << 16; float f;
    __builtin_memcpy(&f, &x, sizeof(f));
    return f;
}
__device__ __forceinline__ unsigned short f2us(float f) {
    __hip_bfloat16 h = __float2bfloat16(f);
    unsigned short s;
    __builtin_memcpy(&s, &h, sizeof(s));
    return s;
}
__device__ __forceinline__ f32x2 mk2(float a, float b) {
    f32x2 r; r[0] = a; r[1] = b; return r;
}
__device__ __forceinline__ f32x2 pkfma(f32x2 a, f32x2 b, f32x2 c) {
#if __has_builtin(__builtin_elementwise_fma)
    return __builtin_elementwise_fma(a, b, c);
#else
    f32x2 r; r[0] = fmaf(a[0], b[0], c[0]); r[1] = fmaf(a[1], b[1], c[1]);
    return r;
#endif
}

// ------------- hist (+rank) + all weight packing ----------------------------
__global__ __launch_bounds__(256) void k_hist(
        const int* __restrict__ dst, int* __restrict__ cnt,
        int* __restrict__ rank,
        const float* __restrict__ f0, const float* __restrict__ f1,
        const float* __restrict__ l1w, const float* __restrict__ scw,
        const float* __restrict__ l2w, const float* __restrict__ aw,
        unsigned short* __restrict__ w0p, unsigned short* __restrict__ w2p,
        unsigned short* __restrict__ wnp) {
    int i = blockIdx.x * 256 + threadIdx.x;
    if (i < NE) rank[i] = atomicAdd(&cnt[dst[i]], 1);  // rank within dst seg
    if (i < 4096) {                     // w0p [l][nt4][lane][i8], 0.25 folded
        int l = i >> 11, r = i & 2047;
        int nt = r >> 9, lane = (r >> 3) & 63, ii = r & 7;
        int k = (lane >> 4) * 8 + ii;
        int j = nt * 16 + (lane & 15);
        float v = (k < 16) ? 0.25f * f0[l * 1024 + k * 64 + j] : 0.f;
        w0p[i] = f2us(v);
    }
    if (i < 16384) {                    // w2p [l][kt*2+nt][lane][i8]
        int l = i >> 13, r = i & 8191;
        int g = r >> 9;
        int kt = g >> 1, nt = g & 1;
        int lane = (r >> 3) & 63, ii = r & 7;
        int K = kt * 32 + (lane >> 4) * 8 + ii;
        int j = K >> 2, v = K & 3;
        int u = nt * 16 + (lane & 15);
        w2p[i] = f2us(f1[l * 8192 + j * 128 + u * 4 + v]);
    }
    if (i < 57344) {                    // wnp [l][tile7][kt8][lane][i8]
        int l = i / 28672, r = i % 28672;
        int tile = r >> 12;
        int r2 = r & 4095;
        int kt = r2 >> 9, lane = (r2 >> 3) & 63, ii = r2 & 7;
        int k = kt * 32 + (lane >> 4) * 8 + ii;   // K = u*8+v
        int u = k >> 3, v = k & 7;
        int col = lane & 15;
        int uvb = l * 8192 + (u * 8 + v) * 32;
        float val;
        if (tile < 2)      val = l1w[uvb + tile * 16 + col];
        else if (tile < 4) val = scw[uvb + (tile - 2) * 16 + col];
        else if (tile < 6) val = l2w[uvb + (tile - 4) * 16 + col];
        else               val = (col == 0) ? aw[l * 256 + u * 8 + v] : 0.f;
        wnp[i] = f2us(val);
    }
}

// ------------------------- 3-phase parallel scan ----------------------------
__global__ __launch_bounds__(256) void k_scan1(const int* __restrict__ cnt,
                                               int* __restrict__ bsum) {
    __shared__ int s[256];
    int t = threadIdx.x;
    int i = blockIdx.x * 256 + t;
    s[t] = (i < NN) ? cnt[i] : 0;
    __syncthreads();
    for (int d = 128; d > 0; d >>= 1) {
        if (t < d) s[t] += s[t + d];
        __syncthreads();
    }
    if (t == 0) bsum[blockIdx.x] = s[0];
}

__global__ __launch_bounds__(256) void k_scan2(int* __restrict__ bsum) {
    __shared__ int s[256];
    int t = threadIdx.x;
    int v = (t < SCAN_BLOCKS) ? bsum[t] : 0;
    s[t] = v; __syncthreads();
    for (int d = 1; d < 256; d <<= 1) {
        int x = (t >= d) ? s[t - d] : 0;
        __syncthreads();
        s[t] += x;
        __syncthreads();
    }
    if (t < SCAN_BLOCKS) bsum[t] = s[t] - v;   // exclusive
}

__global__ __launch_bounds__(256) void k_scan3(
        const int* __restrict__ cnt, const int* __restrict__ bsum,
        int* __restrict__ off, int* __restrict__ cur) {
    __shared__ int s[256];
    int t = threadIdx.x;
    int i = blockIdx.x * 256 + t;
    int v = (i < NN) ? cnt[i] : 0;
    s[t] = v; __syncthreads();
    for (int d = 1; d < 256; d <<= 1) {
        int x = (t >= d) ? s[t - d] : 0;
        __syncthreads();
        s[t] += x;
        __syncthreads();
    }
    int excl = s[t] - v + bsum[blockIdx.x];
    if (i < NN) { off[i] = excl; cur[i] = excl; }
    if (i == NN - 1) off[NN] = excl + v;       // == NE
}

// ---- wave-local staging: wave w stages node rows w*16 .. w*16+15 -----------
__device__ __forceinline__ void stage_xy_wl(const float* __restrict__ nf,
                                            const float* __restrict__ nattr,
                                            long n0, int w, int lane,
                                            f32a* Xs, f32a* Ys) {
    {
        int row = w * 16 + (lane >> 2), u = (lane & 3) * 8;
        long e = (n0 + row) * 32 + u;
        f32a* d = &Xs[row * 33 + u];
        if (e + 8 <= (long)NN * 32) {
            const float4* p = (const float4*)(nf + e);
            float4 q0 = p[0], q1 = p[1];
            d[0]=q0.x; d[1]=q0.y; d[2]=q0.z; d[3]=q0.w;
            d[4]=q1.x; d[5]=q1.y; d[6]=q1.z; d[7]=q1.w;
        } else {
#pragma unroll
            for (int i = 0; i < 8; i++)
                d[i] = (e + i < (long)NN * 32) ? nf[e + i] : 0.f;
        }
    }
    if (lane < 32) {
        int row = w * 16 + (lane >> 1), v = (lane & 1) * 4;
        long e = (n0 + row) * 8 + v;
        f32a* d = &Ys[row * 9 + v];
        if (e + 4 <= (long)NN * 8) {
            float4 q = *(const float4*)(nattr + e);
            d[0]=q.x; d[1]=q.y; d[2]=q.z; d[3]=q.w;
        } else {
#pragma unroll
            for (int i = 0; i < 4; i++)
                d[i] = (e + i < (long)NN * 8) ? nattr[e + i] : 0.f;
        }
    }
}

// ------------- node pre (MFMA): xl = lin1(nf, nattr), layer 0 only ----------
__global__ __launch_bounds__(256) void k_npre_m(
        const float* __restrict__ nf, const float* __restrict__ nattr,
        const unsigned short* __restrict__ wnp_l, float* __restrict__ xl) {
    __shared__ f32a Xs[64 * 33];
    __shared__ f32a Ys[64 * 9];
    const int t = threadIdx.x;
    const int lane = t & 63, w = t >> 6;
    const long n0 = (long)blockIdx.x * 64;
    stage_xy_wl(nf, nattr, n0, w, lane, Xs, Ys);
    __builtin_amdgcn_wave_barrier();   // wave-local LDS; DS pipe in-order

    const int l15 = lane & 15, quad = lane >> 4;
    const int nb = w * 16;
    float y[8], xk[8];
#pragma unroll
    for (int v = 0; v < 8; v++) y[v] = Ys[(nb + l15) * 9 + v];
#pragma unroll
    for (int kt = 0; kt < 8; kt++) xk[kt] = Xs[(nb + l15) * 33 + kt * 4 + quad];

    f32x4 a0, a1;
    a0[0]=0.f;a0[1]=0.f;a0[2]=0.f;a0[3]=0.f;
    a1[0]=0.f;a1[1]=0.f;a1[2]=0.f;a1[3]=0.f;
#pragma unroll
    for (int kt = 0; kt < 8; kt++) {
        float xv = xk[kt];
        short8 a;
#pragma unroll
        for (int i = 0; i < 8; i++) a[i] = (short)f2us(xv * y[i]);
        const short8 b0 = *(const short8*)(wnp_l + ((0 * 8 + kt) * 512) + lane * 8);
        const short8 b1 = *(const short8*)(wnp_l + ((1 * 8 + kt) * 512) + lane * 8);
        a0 = __builtin_amdgcn_mfma_f32_16x16x32_bf16(a, b0, a0, 0, 0, 0);
        a1 = __builtin_amdgcn_mfma_f32_16x16x32_bf16(a, b1, a1, 0, 0, 0);
    }
#pragma unroll
    for (int r = 0; r < 4; r++) {
        long n = n0 + nb + quad * 4 + r;
        if (n < NN) {
            xl[n * 32 + l15]      = a0[r] * 0.0625f;
            xl[n * 32 + 16 + l15] = a1[r] * 0.0625f;
        }
    }
}

// ------------- per-wave edge kernel (r23: rank-based pm, no atomic) ---------
__global__ __launch_bounds__(256) void k_edge_w(
        const float* __restrict__ esc, const int* __restrict__ srcp,
        const int* __restrict__ edst, const int* __restrict__ off,
        const int* __restrict__ rank,
        const float* __restrict__ ea_in,
        float* __restrict__ ea_out, const float* __restrict__ xl,
        const unsigned short* __restrict__ w0p,
        const unsigned short* __restrict__ w2p,
        const float* __restrict__ sew, unsigned short* __restrict__ ef_bf) {
    __shared__ __align__(16) unsigned char SCR[4][8704];

    const int t = threadIdx.x;
    const int w = t >> 6, lane = t & 63;
    const int l15 = lane & 15, quad = lane >> 4;
    const long e0 = ((long)blockIdx.x * 4 + w) * 64;
    u16a* Hs = (u16a*)SCR[w];
    f32a* Ts = (f32a*)SCR[w];

    // ---- entry: scalars + ea rows; pm = off[dst] + rank (loads, no atomic) -
    const long ge = e0 + lane;
    const int src = srcp[ge];
    const int dst = edst[ge];
    const int rk  = rank[ge];
    const int pm  = off[dst] + rk;       // off: 200KB, L2-resident, 16x reuse
    const float4 ea3 = ((const float4*)ea_in)[ge];
    float4 eaq[4];
#pragma unroll
    for (int mt = 0; mt < 4; mt++)
        eaq[mt] = ((const float4*)ea_in)[e0 + mt * 16 + l15];

    // ---- phase 1: H = sin(esc @ w0) -> Hs (bf16) ---------------------------
    short8 bw0[4];
#pragma unroll
    for (int nt = 0; nt < 4; nt++)
        bw0[nt] = *(const short8*)(w0p + (nt * 64 + lane) * 8);
#pragma unroll
    for (int mt = 0; mt < 4; mt++) {
        int row = mt * 16 + l15;
        short8 a;
#pragma unroll
        for (int i = 0; i < 8; i++) a[i] = 0;
        if (quad < 2) {
            const float4* ep = (const float4*)(esc + (e0 + row) * 16 + quad * 8);
            float4 p0 = ep[0], p1 = ep[1];
            a[0]=(short)f2us(p0.x); a[1]=(short)f2us(p0.y);
            a[2]=(short)f2us(p0.z); a[3]=(short)f2us(p0.w);
            a[4]=(short)f2us(p1.x); a[5]=(short)f2us(p1.y);
            a[6]=(short)f2us(p1.z); a[7]=(short)f2us(p1.w);
        }
#pragma unroll
        for (int nt = 0; nt < 4; nt++) {
            f32x4 c; c[0]=0.f; c[1]=0.f; c[2]=0.f; c[3]=0.f;
            c = __builtin_amdgcn_mfma_f32_16x16x32_bf16(a, bw0[nt], c, 0, 0, 0);
#pragma unroll
            for (int r = 0; r < 4; r++) {
                int edge = mt * 16 + quad * 4 + r;
                int j = nt * 16 + l15;
                Hs[edge * 68 + j] = f2us(__sinf(c[r]));
            }
        }
    }
    // per-wave LDS only: compiler fence (0 instrs); DS pipe is in-order.
    __builtin_amdgcn_wave_barrier();

    // ---- issue xl gather now; lands under phase-2 MFMA ---------------------
    const float4* xp = (const float4*)(xl + (long)src * 32);
    float4 xq[8];
#pragma unroll
    for (int g = 0; g < 8; g++) xq[g] = xp[g];

    // ---- phase 2: T = (H (x) ea) @ w2, kt-outer so B-frags load once -------
    f32x4 acc[4][2];
#pragma unroll
    for (int mt = 0; mt < 4; mt++)
#pragma unroll
        for (int nt = 0; nt < 2; nt++) {
            acc[mt][nt][0]=0.f; acc[mt][nt][1]=0.f;
            acc[mt][nt][2]=0.f; acc[mt][nt][3]=0.f;
        }
#pragma unroll
    for (int kt = 0; kt < 8; kt++) {
        const short8 b0 = *(const short8*)(w2p + ((kt*2+0)*64 + lane) * 8);
        const short8 b1 = *(const short8*)(w2p + ((kt*2+1)*64 + lane) * 8);
#pragma unroll
        for (int mt = 0; mt < 4; mt++) {
            int row = mt * 16 + l15;
            unsigned int hp = *(const u32a*)(Hs + row * 68 + kt * 8 + quad * 2);
            float H0 = us2f(hp & 0xFFFFu), H1 = us2f(hp >> 16);
            float4 eav = eaq[mt];
            short8 a;
            a[0]=(short)f2us(H0*eav.x); a[1]=(short)f2us(H0*eav.y);
            a[2]=(short)f2us(H0*eav.z); a[3]=(short)f2us(H0*eav.w);
            a[4]=(short)f2us(H1*eav.x); a[5]=(short)f2us(H1*eav.y);
            a[6]=(short)f2us(H1*eav.z); a[7]=(short)f2us(H1*eav.w);
            acc[mt][0] = __builtin_amdgcn_mfma_f32_16x16x32_bf16(a, b0, acc[mt][0], 0, 0, 0);
            acc[mt][1] = __builtin_amdgcn_mfma_f32_16x16x32_bf16(a, b1, acc[mt][1], 0, 0, 0);
        }
    }
    __builtin_amdgcn_wave_barrier();

    // ---- phase 3: transpose T via LDS (0.5 of ef folded into scale) --------
#pragma unroll
    for (int mt = 0; mt < 4; mt++)
#pragma unroll
        for (int nt = 0; nt < 2; nt++)
#pragma unroll
            for (int r = 0; r < 4; r++)
                Ts[(mt*16 + quad*4 + r) * 34 + nt*16 + l15] = acc[mt][nt][r] * 0.0625f;
    __builtin_amdgcn_wave_barrier();

    // ---- epilogue: tvp/efp pairs + k-pair pk eo (r19 verified) -------------
    {
        f32x2 tvp[16];
#pragma unroll
        for (int i = 0; i < 16; i++)
            tvp[i] = *(const f32x2a*)(Ts + lane * 34 + i * 2);   // ds_read_b64
        f32x2 efp[16];
#pragma unroll
        for (int g = 0; g < 8; g++) {
            float4 xv = xq[g];
            efp[2*g]   = mk2(xv.x, xv.y) * tvp[2*g];
            efp[2*g+1] = mk2(xv.z, xv.w) * tvp[2*g+1];
        }
        uint4* efo = (uint4*)(ef_bf + (long)pm * 32);
#pragma unroll
        for (int g = 0; g < 4; g++) {
            uint4 wv;
            wv.x = (unsigned)f2us(efp[4*g+0][0]) | ((unsigned)f2us(efp[4*g+0][1]) << 16);
            wv.y = (unsigned)f2us(efp[4*g+1][0]) | ((unsigned)f2us(efp[4*g+1][1]) << 16);
            wv.z = (unsigned)f2us(efp[4*g+2][0]) | ((unsigned)f2us(efp[4*g+2][1]) << 16);
            wv.w = (unsigned)f2us(efp[4*g+3][0]) | ((unsigned)f2us(efp[4*g+3][1]) << 16);
            efo[g] = wv;
        }
        float ea[4] = {ea3.x, ea3.y, ea3.z, ea3.w};
        f32x2 eo01 = {0.f, 0.f}, eo23 = {0.f, 0.f};
#pragma unroll
        for (int u = 0; u < 32; u++) {
            float efu = efp[u >> 1][u & 1];
#pragma unroll
            for (int v = 0; v < 4; v++) {
                float p = efu * ea[v];
                f32x2 pp = mk2(p, p);
                const f32x2 s01 = *(const f32x2a*)(sew + (u * 4 + v) * 4);
                const f32x2 s23 = *(const f32x2a*)(sew + (u * 4 + v) * 4 + 2);
                eo01 = pkfma(pp, s01, eo01);
                eo23 = pkfma(pp, s23, eo23);
            }
        }
        constexpr float SCE_SCALE = 0.02209708691f;
        float4 o;
        o.x = ea3.x + eo01[0] * SCE_SCALE;
        o.y = ea3.y + eo01[1] * SCE_SCALE;
        o.z = ea3.z + eo23[0] * SCE_SCALE;
        o.w = ea3.w + eo23[1] * SCE_SCALE;
        ((float4*)ea_out)[ge] = o;
    }
}

// --------- gather (16 lanes/node) + node post + fused next-layer npre -------
__global__ __launch_bounds__(256) void k_gpost_m(
        const int* __restrict__ off, const unsigned short* __restrict__ ef,
        const float* __restrict__ nf_cur, const float* __restrict__ nattr,
        const unsigned short* __restrict__ wnp_l,
        float* __restrict__ nf_next, float* __restrict__ out_nf, int last,
        const unsigned short* __restrict__ wnp_next,
        float* __restrict__ xl_out) {
    __shared__ f32a Xs[64 * 33];
    __shared__ f32a As[64 * 33];
    __shared__ f32a Ys[64 * 9];
    const int t = threadIdx.x;
    const int lane = t & 63, w = t >> 6;
    const long n0 = (long)blockIdx.x * 64;
    stage_xy_wl(nf_cur, nattr, n0, w, lane, Xs, Ys);

    {   // gather: 16 lanes/node, 4 r-interleaved streams (serial chain ~4)
        int g = (lane >> 2) & 3, l4 = lane & 3;
#pragma unroll
        for (int batch = 0; batch < 4; batch++) {
            int nl = w * 16 + batch * 4 + (lane >> 4);
            long n = n0 + nl;
            float v[8] = {0.f,0.f,0.f,0.f,0.f,0.f,0.f,0.f};
            if (n < NN) {
                int b = off[n] + g, en = off[n + 1];
                for (int r = b; r < en; r += 4) {
                    uint4 q = *(const uint4*)(ef + (long)r * 32 + l4 * 8);
                    v[0] += us2f(q.x & 0xFFFFu); v[1] += us2f(q.x >> 16);
                    v[2] += us2f(q.y & 0xFFFFu); v[3] += us2f(q.y >> 16);
                    v[4] += us2f(q.z & 0xFFFFu); v[5] += us2f(q.z >> 16);
                    v[6] += us2f(q.w & 0xFFFFu); v[7] += us2f(q.w >> 16);
                }
            }
#pragma unroll
            for (int i = 0; i < 8; i++) {
                v[i] += __shfl_xor(v[i], 4);
                v[i] += __shfl_xor(v[i], 8);
            }
            if (g == 0) {
#pragma unroll
                for (int i = 0; i < 8; i++)
                    As[nl * 33 + l4 * 8 + i] = v[i] * 0.25f;
            }
        }
    }
    __builtin_amdgcn_wave_barrier();   // all LDS wave-local

    const int l15 = lane & 15, quad = lane >> 4;
    const int nb = w * 16;
    float y[8], xk[8], ak[8];
#pragma unroll
    for (int v = 0; v < 8; v++) y[v] = Ys[(nb + l15) * 9 + v];
#pragma unroll
    for (int kt = 0; kt < 8; kt++) {
        xk[kt] = Xs[(nb + l15) * 33 + kt * 4 + quad];
        ak[kt] = As[(nb + l15) * 33 + kt * 4 + quad];
    }
    f32x4 sc0, sc1, l20, l21, al;
    sc0[0]=0.f;sc0[1]=0.f;sc0[2]=0.f;sc0[3]=0.f;
    sc1 = sc0; l20 = sc0; l21 = sc0; al = sc0;
#pragma unroll
    for (int kt = 0; kt < 8; kt++) {
        float xv = xk[kt], av = ak[kt];
        short8 ax, ag;
#pragma unroll
        for (int i = 0; i < 8; i++) {
            ax[i] = (short)f2us(xv * y[i]);
            ag[i] = (short)f2us(av * y[i]);
        }
        const short8 b2 = *(const short8*)(wnp_l + ((2 * 8 + kt) * 512) + lane * 8);
        const short8 b3 = *(const short8*)(wnp_l + ((3 * 8 + kt) * 512) + lane * 8);
        const short8 b4 = *(const short8*)(wnp_l + ((4 * 8 + kt) * 512) + lane * 8);
        const short8 b5 = *(const short8*)(wnp_l + ((5 * 8 + kt) * 512) + lane * 8);
        const short8 b6 = *(const short8*)(wnp_l + ((6 * 8 + kt) * 512) + lane * 8);
        sc0 = __builtin_amdgcn_mfma_f32_16x16x32_bf16(ax, b2, sc0, 0, 0, 0);
        sc1 = __builtin_amdgcn_mfma_f32_16x16x32_bf16(ax, b3, sc1, 0, 0, 0);
        l20 = __builtin_amdgcn_mfma_f32_16x16x32_bf16(ag, b4, l20, 0, 0, 0);
        l21 = __builtin_amdgcn_mfma_f32_16x16x32_bf16(ag, b5, l21, 0, 0, 0);
        al  = __builtin_amdgcn_mfma_f32_16x16x32_bf16(ag, b6, al,  0, 0, 0);
    }
#pragma unroll
    for (int r = 0; r < 4; r++) {
        float alpha = __shfl(al[r], quad * 16) * 0.0625f;  // col 0 of alpha tile
        long n = n0 + nb + quad * 4 + r;
        float o0 = sc0[r] * 0.0625f + alpha * (l20[r] * 0.0625f);
        float o1 = sc1[r] * 0.0625f + alpha * (l21[r] * 0.0625f);
        if (last) {
            if (n < NN) {
                out_nf[n * 32 + l15]      = o0;
                out_nf[n * 32 + 16 + l15] = o1;
            }
        } else {
            float t0 = __sinf(o0), t1 = __sinf(o1);
            if (n < NN) {
                nf_next[n * 32 + l15]      = t0;
                nf_next[n * 32 + 16 + l15] = t1;
            }
            // stage next-layer X into wave-local Xs (xk already consumed)
            Xs[(nb + quad * 4 + r) * 33 + l15]      = t0;
            Xs[(nb + quad * 4 + r) * 33 + 16 + l15] = t1;
        }
    }
    if (!last) {   // fused next-layer npre: xl_out = lin1_{l+1}(sin(o), nattr)
        __builtin_amdgcn_wave_barrier();
        float xk2[8];
#pragma unroll
        for (int kt = 0; kt < 8; kt++)
            xk2[kt] = Xs[(nb + l15) * 33 + kt * 4 + quad];
        f32x4 a0, a1;
        a0[0]=0.f;a0[1]=0.f;a0[2]=0.f;a0[3]=0.f;
        a1 = a0;
#pragma unroll
        for (int kt = 0; kt < 8; kt++) {
            float xv = xk2[kt];
            short8 a;
#pragma unroll
            for (int i = 0; i < 8; i++) a[i] = (short)f2us(xv * y[i]);
            const short8 b0 = *(const short8*)(wnp_next + ((0 * 8 + kt) * 512) + lane * 8);
            const short8 b1 = *(const short8*)(wnp_next + ((1 * 8 + kt) * 512) + lane * 8);
            a0 = __builtin_amdgcn_mfma_f32_16x16x32_bf16(a, b0, a0, 0, 0, 0);
            a1 = __builtin_amdgcn_mfma_f32_16x16x32_bf16(a, b1, a1, 0, 0, 0);
        }
#pragma unroll
        for (int r = 0; r < 4; r++) {
            long n = n0 + nb + quad * 4 + r;
            if (n < NN) {
                xl_out[n * 32 + l15]      = a0[r] * 0.0625f;
                xl_out[n * 32 + 16 + l15] = a1[r] * 0.0625f;
            }
        }
    }
}

// ---------------------------------------------------------------------------
extern "C" void kernel_launch(void* const* d_in, const int* in_sizes, int n_in,
                              void* d_out, int out_size, void* d_ws, size_t ws_size,
                              hipStream_t stream) {
    int I_nf, I_na, I_esrc, I_edst, I_ea, I_esc, I_sc, I_l1, I_l2, I_al, I_se, I_f0, I_f1;
    if (in_sizes[0] == 1600000) {            // dict order
        I_nf=0; I_na=1; I_esrc=2; I_edst=3; I_ea=4; I_esc=5;
        I_sc=6; I_l1=7; I_l2=8; I_al=9; I_se=10; I_f0=11; I_f1=12;
    } else {                                  // sorted keys
        I_al=0; I_ea=1; I_edst=2; I_esc=3; I_esrc=4; I_f0=5; I_f1=6;
        I_l1=7; I_l2=8; I_na=9; I_nf=10; I_sc=11; I_se=12;
    }
    const float* nf_in = (const float*)d_in[I_nf];
    const float* na    = (const float*)d_in[I_na];
    const int*   esrc  = (const int*)d_in[I_esrc];
    const int*   edst  = (const int*)d_in[I_edst];
    const float* ea_in = (const float*)d_in[I_ea];
    const float* escl  = (const float*)d_in[I_esc];
    const float* w_sc  = (const float*)d_in[I_sc];
    const float* w_l1  = (const float*)d_in[I_l1];
    const float* w_l2  = (const float*)d_in[I_l2];
    const float* w_al  = (const float*)d_in[I_al];
    const float* w_se  = (const float*)d_in[I_se];
    const float* w_f0  = (const float*)d_in[I_f0];
    const float* w_f1  = (const float*)d_in[I_f1];

    float* ws = (float*)d_ws;
    float* out_nf = (float*)d_out;              // f32 [50000*32]
    float* out_ea = out_nf + (long)NN * 32;     // f32 [800000*4]

    unsigned short* w0p     = (unsigned short*)(ws + OFF_W0P);
    unsigned short* w2p     = (unsigned short*)(ws + OFF_W2P);
    unsigned short* wnp     = (unsigned short*)(ws + OFF_WNP);
    int*            csr_off = (int*)(ws + OFF_OFF);
    int*            csr_cur = (int*)(ws + OFF_CUR);
    int*            rank    = (int*)(ws + OFF_PERM);
    int*            bsum    = (int*)(ws + OFF_BSUM);
    unsigned short* ef_bf   = (unsigned short*)(ws + OFF_EF);

    hipMemsetAsync(csr_cur, 0, NN * sizeof(int), stream);
    k_hist<<<3125, 256, 0, stream>>>(edst, csr_cur, rank, w_f0, w_f1,
                                     w_l1, w_sc, w_l2, w_al, w0p, w2p, wnp);
    k_scan1<<<SCAN_BLOCKS, 256, 0, stream>>>(csr_cur, bsum);
    k_scan2<<<1, 256, 0, stream>>>(bsum);
    k_scan3<<<SCAN_BLOCKS, 256, 0, stream>>>(csr_cur, bsum, csr_off, csr_cur);

    for (int l = 0; l < 2; l++) {
        int last = (l == 1);
        const float* nf_cur = (l == 0) ? nf_in : (ws + OFF_NF);
        const float* ea_cur = (l == 0) ? ea_in : out_ea;

        if (l == 0)
            k_npre_m<<<782, 256, 0, stream>>>(nf_cur, na, wnp,
                                              out_nf /*xl scratch*/);
        k_edge_w<<<3125, 256, 0, stream>>>(escl, esrc, edst, csr_off, rank,
                                           ea_cur, out_ea,
                                           out_nf /*xl*/, w0p + l * 2048,
                                           w2p + l * 8192, w_se + l * 512,
                                           ef_bf);
        k_gpost_m<<<782, 256, 0, stream>>>(csr_off, ef_bf,
                                           nf_cur, na, wnp + l * 28672,
                                           ws + OFF_NF, out_nf, last,
                                           wnp + 28672 /*next layer*/,
                                           out_nf /*xl for next layer*/);
    }
}